// Round 1
// baseline (91.705 us; speedup 1.0000x reference)
//
#include <hip/hip_runtime.h>

// Problem constants
constexpr int Cc = 64, Oc = 64, Gc = 16, Ec = 128, Wc = 7;
constexpr int Dc = 4, Nc = 4, Bc = 2, Tc = 512, TTc = 256, FOc = 64;
constexpr float EPSf = 1e-5f, LEAKYf = 0.01f;
// M = B*D*E*t*W = 2*4*128*256*7
constexpr float Minv = 1.0f / 1835008.0f;

// acc layout in ws: acc[slot<8][which<2][o<64]  (which 0 = sum(x*w), 1 = sum(x^2*w^2))

__global__ __launch_bounds__(256) void stats_k(const float* __restrict__ x,
                                               const float* __restrict__ wgt,
                                               float* __restrict__ acc) {
  int bid = blockIdx.x;          // (b, g, fo)
  int fo  = bid & 63;
  int g   = (bid >> 6) & 15;
  int b   = bid >> 10;
  int tid = threadIdx.x;
  int d    = tid >> 6;           // wave id = kernel-depth index
  int lane = tid & 63;

  __shared__ float part[4][4][2];

  float m_tot = 0.f, v_tot = 0.f;
#pragma unroll
  for (int f2 = 0; f2 < 2; ++f2) {
    int f = 2 * fo + f2;
    const float4* row4 =
        (const float4*)(x + ((size_t)((b * Cc + g * Dc + d) * Ec + f)) * Tc);
    float4 v0 = row4[lane];        // t = 4*lane   .. +3
    float4 v1 = row4[lane + 64];   // t = 4*lane+256 .. +3
    float se  = v0.x + v0.z + v1.x + v1.z;                       // even t
    float so  = v0.y + v0.w + v1.y + v1.w;                       // odd t
    float se2 = v0.x * v0.x + v0.z * v0.z + v1.x * v1.x + v1.z * v1.z;
    float so2 = v0.y * v0.y + v0.w * v0.w + v1.y * v1.y + v1.w * v1.w;
#pragma unroll
    for (int off = 1; off < 64; off <<= 1) {
      se  += __shfl_xor(se, off);
      so  += __shfl_xor(so, off);
      se2 += __shfl_xor(se2, off);
      so2 += __shfl_xor(so2, off);
    }
    float x0   = __shfl(v0.x, 0);
    float x1   = __shfl(v0.y, 0);
    float x509 = __shfl(v1.y, 63);
    float x510 = __shfl(v1.z, 63);
    float x511 = __shfl(v1.w, 63);
    if (lane < 4) {
      // window sums over t for each w (parity sums minus edge corrections)
      float ws0 = so - x509 - x511, ws1 = se - x510, ws2 = so - x511;
      float ws3 = se, ws4 = so, ws5 = se - x0, ws6 = so - x1;
      float q0 = so2 - x509 * x509 - x511 * x511, q1 = se2 - x510 * x510;
      float q2 = so2 - x511 * x511, q3 = se2, q4 = so2;
      float q5 = se2 - x0 * x0, q6 = so2 - x1 * x1;
      int o = g * Nc + lane;
      const float* wp = wgt + ((size_t)((o * Dc + d) * Ec + f)) * Wc;
      float w0 = wp[0], w1 = wp[1], w2 = wp[2], w3 = wp[3], w4 = wp[4],
            w5 = wp[5], w6 = wp[6];
      m_tot += ws0 * w0 + ws1 * w1 + ws2 * w2 + ws3 * w3 + ws4 * w4 +
               ws5 * w5 + ws6 * w6;
      v_tot += q0 * w0 * w0 + q1 * w1 * w1 + q2 * w2 * w2 + q3 * w3 * w3 +
               q4 * w4 * w4 + q5 * w5 * w5 + q6 * w6 * w6;
    }
  }
  if (lane < 4) {
    part[d][lane][0] = m_tot;
    part[d][lane][1] = v_tot;
  }
  __syncthreads();
  if (tid < 8) {
    int n = tid >> 1, which = tid & 1;
    float tot = part[0][n][which] + part[1][n][which] + part[2][n][which] +
                part[3][n][which];
    int o = g * Nc + n;
    int slot = bid & 7;   // spread atomic contention over 8 slots
    atomicAdd(&acc[(slot * 2 + which) * 64 + o], tot);
  }
}

// Conv + BN + pool + LeakyReLU.
// LDS x layout is transposed: element q (q = t + 4, pads at q<4 and q>=516)
// stored at (q&7)*65 + (q>>3). Compute reads element 8*j + (1 + i), which
// becomes stride-1 across lanes j -> conflict-free, with constant offsets.
__global__ __launch_bounds__(256) void conv_k(const float* __restrict__ x,
                                              const float* __restrict__ wgt,
                                              const float* __restrict__ gamma,
                                              const float* __restrict__ beta,
                                              const float* __restrict__ acc,
                                              float* __restrict__ out) {
  int bid = blockIdx.x;          // (b, g, fo) — same mapping as stats_k
  int fo  = bid & 63;
  int g   = (bid >> 6) & 15;
  int b   = bid >> 10;
  int tid = threadIdx.x;

  __shared__ float xs[8 * 520];  // 8 rows (d*2+f2), transposed layout
  __shared__ float wsm[224];     // [(n*4+d)*2+f2]*7 + w
  __shared__ float sA[4], sC[4];

  {  // stage x (each row: 512 floats, via float4, scattered into transposed LDS)
    int f2 = tid >> 7;
    int j  = tid & 127;
#pragma unroll
    for (int dd = 0; dd < 4; ++dd) {
      const float4* src = (const float4*)(
          x + ((size_t)((b * Cc + g * Dc + dd) * Ec + 2 * fo + f2)) * Tc);
      float4 v  = src[j];
      float* row = &xs[(dd * 2 + f2) * 520];
      int q0 = 4 + 4 * j;
      row[((q0 + 0) & 7) * 65 + ((q0 + 0) >> 3)] = v.x;
      row[((q0 + 1) & 7) * 65 + ((q0 + 1) >> 3)] = v.y;
      row[((q0 + 2) & 7) * 65 + ((q0 + 2) >> 3)] = v.z;
      row[((q0 + 3) & 7) * 65 + ((q0 + 3) >> 3)] = v.w;
    }
  }
  if (tid < 64) {  // zero the pad elements q in {0..3, 516..519}
    int r = tid >> 3, jj = tid & 7;
    int q = (jj < 4) ? jj : (512 + jj);
    xs[r * 520 + (q & 7) * 65 + (q >> 3)] = 0.f;
  }
  if (tid < 224) {  // stage weights for this (g, f-pair)
    int n = tid / 56, rr = tid % 56;
    int dd = rr / 14, r2 = rr % 14;
    int f2 = r2 / 7, w = r2 % 7;
    int o = g * Nc + n;
    wsm[tid] = wgt[((size_t)((o * Dc + dd) * Ec + 2 * fo + f2)) * Wc + w];
  } else if (tid < 228) {  // finalize BN stats for the block's 4 output channels
    int n = tid - 224;
    int o = g * Nc + n;
    float msum = 0.f, esum = 0.f;
#pragma unroll
    for (int s = 0; s < 8; ++s) {
      msum += acc[(s * 2 + 0) * 64 + o];
      esum += acc[(s * 2 + 1) * 64 + o];
    }
    float mean = msum * Minv;
    float e2   = esum * Minv;
    float var  = e2 - mean * mean;       // biased var, matches jnp.var
    float a    = gamma[o] * rsqrtf(var + EPSf);
    sA[n] = a;
    sC[n] = 56.0f * (beta[o] - a * mean);  // 2*D*W = 56
  }
  __syncthreads();

  int n = tid >> 6;   // wave id = filter-in-group
  int j = tid & 63;   // thread handles tt = 4j..4j+3
  float a0 = 0.f, a1 = 0.f, a2 = 0.f, a3 = 0.f;
#pragma unroll
  for (int r = 0; r < 8; ++r) {
    const float* row = &xs[r * 520];
    float xv[13];
#pragma unroll
    for (int i = 0; i < 13; ++i) {
      int c = 1 + i;  // element 8j + c -> addr (c&7)*65 + (c>>3) + j
      xv[i] = row[(c & 7) * 65 + (c >> 3) + j];
    }
    const float* wp = &wsm[(n * 8 + r) * 7];
#pragma unroll
    for (int w = 0; w < 7; ++w) {
      float wt = wp[w];
      a0 += xv[w]     * wt;
      a1 += xv[w + 2] * wt;
      a2 += xv[w + 4] * wt;
      a3 += xv[w + 6] * wt;
    }
  }
  float sa = sA[n], sc = sC[n];
  float4 res;
  float r0 = sa * a0 + sc; res.x = (r0 >= 0.f) ? r0 : LEAKYf * r0;
  float r1 = sa * a1 + sc; res.y = (r1 >= 0.f) ? r1 : LEAKYf * r1;
  float r2 = sa * a2 + sc; res.z = (r2 >= 0.f) ? r2 : LEAKYf * r2;
  float r3 = sa * a3 + sc; res.w = (r3 >= 0.f) ? r3 : LEAKYf * r3;
  int o = g * Nc + n;
  float* op = out + ((size_t)((b * Oc + o) * FOc + fo)) * TTc + 4 * j;
  *(float4*)op = res;
}

extern "C" void kernel_launch(void* const* d_in, const int* in_sizes, int n_in,
                              void* d_out, int out_size, void* d_ws, size_t ws_size,
                              hipStream_t stream) {
  (void)in_sizes; (void)n_in; (void)out_size; (void)ws_size;
  const float* x     = (const float*)d_in[0];
  const float* w     = (const float*)d_in[1];
  const float* gamma = (const float*)d_in[2];
  const float* beta  = (const float*)d_in[3];
  float* acc = (float*)d_ws;                       // 1024 floats = 4 KiB
  hipMemsetAsync(acc, 0, 1024 * sizeof(float), stream);
  stats_k<<<dim3(Bc * Gc * FOc), dim3(256), 0, stream>>>(x, w, acc);
  conv_k<<<dim3(Bc * Gc * FOc), dim3(256), 0, stream>>>(x, w, gamma, beta, acc,
                                                        (float*)d_out);
}